// Round 2
// baseline (53.244 us; speedup 1.0000x reference)
//
#include <hip/hip_runtime.h>

// TT-embedding: voc_quant (32,32,32), emb_quant (8,8,16), ranks (1,8,8,1).
// out[n, e0*128+e1*16+e2] = sum_{r1,r2} c0[i0][e0][r1]*c1[i1][r1][e1][r2]*c2[i2][r2][e2]
//
// Two-stage: precompute A[i0][i1][e0*8+e1][r2] = sum_r1 c0*c1 (1024 rows x 512
// floats = 2 MB, L2-resident), then the main kernel is a pure streaming
// contraction with NO LDS and no __syncthreads — write-BW-bound.

#define TT_A_BYTES (1024u * 512u * 4u)

// ---- Kernel 1: A[i0][i1][pair][r2] = sum_r1 c0[i0][e0][r1] * c1[i1][r1][e1][r2]
__global__ __launch_bounds__(256) void tt_precomp_kernel(
    const float* __restrict__ c0,   // [32][8][8]
    const float* __restrict__ c1,   // [32][8][8][8]
    float* __restrict__ A)          // [32][32][64][8]
{
    const int i0 = blockIdx.x >> 5;
    const int i1 = blockIdx.x & 31;
    const float* c0r = c0 + i0 * 64;
    const float* c1r = c1 + i1 * 512;
    float* Ar = A + (size_t)blockIdx.x * 512;

    #pragma unroll
    for (int v = threadIdx.x; v < 512; v += 256) {
        const int pair = v >> 3;            // e0*8 + e1
        const int r2   = v & 7;
        const int e0   = pair >> 3;
        const int e1   = pair & 7;
        float acc = 0.f;
        #pragma unroll
        for (int r1 = 0; r1 < 8; ++r1)
            acc = fmaf(c0r[e0 * 8 + r1], c1r[r1 * 64 + e1 * 8 + r2], acc);
        Ar[v] = acc;
    }
}

// ---- Kernel 2: out[n][pair*16 + e2] = sum_r2 A[i0i1][pair][r2] * c2[i2][r2][e2]
__global__ __launch_bounds__(256) void tt_emb_kernel(
    const int* __restrict__ x,
    const float* __restrict__ A,    // [1024][512]
    const float* __restrict__ c2,   // [32][8][16]
    float* __restrict__ out)        // [N][1024]
{
    const int n = blockIdx.x;
    const int t = threadIdx.x;

    const int flat = x[n];
    const int i0 = (flat >> 10) & 31;
    const int i1 = (flat >> 5) & 31;
    const int i2 = flat & 31;

    const float* Ar  = A + ((size_t)(i0 * 32 + i1)) * 512;
    const float* c2r = c2 + i2 * 128;

    // thread t owns outputs o = 4t .. 4t+3: pair = t>>2, e2 = (t&3)*4 + q
    const int pair = t >> 2;
    const int e2b  = (t & 3) << 2;

    const float4 tlo = *reinterpret_cast<const float4*>(Ar + pair * 8);
    const float4 thi = *reinterpret_cast<const float4*>(Ar + pair * 8 + 4);
    const float tmp[8] = {tlo.x, tlo.y, tlo.z, tlo.w, thi.x, thi.y, thi.z, thi.w};

    float r0 = 0.f, r1 = 0.f, r2v = 0.f, r3 = 0.f;
    #pragma unroll
    for (int r = 0; r < 8; ++r) {
        const float4 cv = *reinterpret_cast<const float4*>(c2r + r * 16 + e2b);
        r0 = fmaf(tmp[r], cv.x, r0);
        r1 = fmaf(tmp[r], cv.y, r1);
        r2v = fmaf(tmp[r], cv.z, r2v);
        r3 = fmaf(tmp[r], cv.w, r3);
    }

    if (flat == 0) { r0 = r1 = r2v = r3 = 0.f; }   // padding_idx

    *reinterpret_cast<float4*>(out + (size_t)n * 1024 + (size_t)t * 4) =
        make_float4(r0, r1, r2v, r3);
}

// ---- Fallback (ws too small): round-1 LDS kernel, known-good at 39.5 us
__global__ __launch_bounds__(256) void tt_emb_lds_kernel(
    const int* __restrict__ x,
    const float* __restrict__ c0,
    const float* __restrict__ c1,
    const float* __restrict__ c2,
    float* __restrict__ out)
{
    const int n = blockIdx.x;
    const int t = threadIdx.x;

    __shared__ float s0[64];
    __shared__ float s1[512];
    __shared__ float s2[128];

    const int flat = x[n];
    const int i0 = (flat >> 10) & 31;
    const int i1 = (flat >> 5) & 31;
    const int i2 = flat & 31;

    if (t < 64)  s0[t] = c0[i0 * 64 + t];
    s1[t]        = c1[i1 * 512 + t];
    s1[t + 256]  = c1[i1 * 512 + 256 + t];
    if (t < 128) s2[t] = c2[i2 * 128 + t];
    __syncthreads();

    const int e0  = t >> 5;
    const int e1  = (t >> 2) & 7;
    const int e2b = (t & 3) << 2;

    float tmp[8] = {0.f, 0.f, 0.f, 0.f, 0.f, 0.f, 0.f, 0.f};
    #pragma unroll
    for (int r1 = 0; r1 < 8; ++r1) {
        const float a = s0[e0 * 8 + r1];
        #pragma unroll
        for (int r2 = 0; r2 < 8; ++r2)
            tmp[r2] = fmaf(a, s1[r1 * 64 + e1 * 8 + r2], tmp[r2]);
    }

    float res[4];
    #pragma unroll
    for (int q = 0; q < 4; ++q) {
        float acc = 0.f;
        #pragma unroll
        for (int r2 = 0; r2 < 8; ++r2)
            acc = fmaf(tmp[r2], s2[r2 * 16 + e2b + q], acc);
        res[q] = acc;
    }

    if (flat == 0) { res[0] = res[1] = res[2] = res[3] = 0.f; }

    *reinterpret_cast<float4*>(out + (size_t)n * 1024 + (size_t)t * 4) =
        make_float4(res[0], res[1], res[2], res[3]);
}

extern "C" void kernel_launch(void* const* d_in, const int* in_sizes, int n_in,
                              void* d_out, int out_size, void* d_ws, size_t ws_size,
                              hipStream_t stream) {
    const int*   x  = (const int*)d_in[0];     // 32768 indices
    const float* c0 = (const float*)d_in[1];   // 2048 floats
    const float* c1 = (const float*)d_in[2];   // 16384 floats
    const float* c2 = (const float*)d_in[3];   // 4096 floats
    float* out = (float*)d_out;                // 33554432 fp32

    const int N = in_sizes[0];                 // 32768

    if (ws_size >= TT_A_BYTES) {
        float* A = (float*)d_ws;
        tt_precomp_kernel<<<1024, 256, 0, stream>>>(c0, c1, A);
        tt_emb_kernel<<<N, 256, 0, stream>>>(x, A, c2, out);
    } else {
        tt_emb_lds_kernel<<<N, 256, 0, stream>>>(x, c0, c1, c2, out);
    }
}